// Round 7
// baseline (173.482 us; speedup 1.0000x reference)
//
#include <hip/hip_runtime.h>
#include <hip/hip_bf16.h>

// Problem constants
#define T_ 8192
#define H_ 64
#define X_ 128
#define C_ 128   // chunks
#define L_ 64    // chunk length
#define MS 68    // LDS matrix row stride (floats)

// workspace float offsets
#define OFF_P   (T_ * H_)              // P[13][4096]: A^(2^s), s=0..12
#define OFF_HS  (OFF_P + 13 * 4096)    // hstart[128][64]
#define OFF_G   (OFF_HS + C_ * H_)     // G[64][4096]: A^(i+1)

// ===========================================================================
// Matrix row held in 16 NAMED float4 registers (no array -> no scratch demotion)
// ===========================================================================
#define ROW_DECL(p) float4 p##q0,p##q1,p##q2,p##q3,p##q4,p##q5,p##q6,p##q7, \
                           p##q8,p##q9,p##q10,p##q11,p##q12,p##q13,p##q14,p##q15

#define ROW_LOAD(p, base) do { const float4* _a4 = (const float4*)(base); \
    p##q0=_a4[0];   p##q1=_a4[1];   p##q2=_a4[2];   p##q3=_a4[3];   \
    p##q4=_a4[4];   p##q5=_a4[5];   p##q6=_a4[6];   p##q7=_a4[7];   \
    p##q8=_a4[8];   p##q9=_a4[9];   p##q10=_a4[10]; p##q11=_a4[11]; \
    p##q12=_a4[12]; p##q13=_a4[13]; p##q14=_a4[14]; p##q15=_a4[15]; } while(0)

#define SC4_(v) do { (v).x*=0.1f; (v).y*=0.1f; (v).z*=0.1f; (v).w*=0.1f; } while(0)
#define ROW_SCALE01(p) do { \
    SC4_(p##q0);  SC4_(p##q1);  SC4_(p##q2);  SC4_(p##q3);  \
    SC4_(p##q4);  SC4_(p##q5);  SC4_(p##q6);  SC4_(p##q7);  \
    SC4_(p##q8);  SC4_(p##q9);  SC4_(p##q10); SC4_(p##q11); \
    SC4_(p##q12); SC4_(p##q13); SC4_(p##q14); SC4_(p##q15); } while(0)

#define DIAG4_(v, qi) do { if ((lane>>2)==(qi)) { (v).x+=_dx; (v).y+=_dy; (v).z+=_dz; (v).w+=_dw; } } while(0)
#define ROW_ADD_DIAG(p) do { \
    const float _dx=((lane&3)==0)?0.9f:0.f, _dy=((lane&3)==1)?0.9f:0.f, \
                _dz=((lane&3)==2)?0.9f:0.f, _dw=((lane&3)==3)?0.9f:0.f; \
    DIAG4_(p##q0,0);   DIAG4_(p##q1,1);   DIAG4_(p##q2,2);   DIAG4_(p##q3,3);   \
    DIAG4_(p##q4,4);   DIAG4_(p##q5,5);   DIAG4_(p##q6,6);   DIAG4_(p##q7,7);   \
    DIAG4_(p##q8,8);   DIAG4_(p##q9,9);   DIAG4_(p##q10,10); DIAG4_(p##q11,11); \
    DIAG4_(p##q12,12); DIAG4_(p##q13,13); DIAG4_(p##q14,14); DIAG4_(p##q15,15); } while(0)

#define MVQ_(vq, idx) do { float4 _h=_h4[idx]; \
    _a0=fmaf((vq).x,_h.x,_a0); _a1=fmaf((vq).y,_h.y,_a1); \
    _a2=fmaf((vq).z,_h.z,_a2); _a3=fmaf((vq).w,_h.w,_a3); } while(0)

// out = row(p) . vec + init    (vec: 16 same-address float4 reads -> broadcast)
#define MV64(p, vecptr, initv, outv) do { \
    const float4* _h4 = (const float4*)(vecptr); \
    float _a0=(initv), _a1=0.f, _a2=0.f, _a3=0.f; \
    MVQ_(p##q0,0);   MVQ_(p##q1,1);   MVQ_(p##q2,2);   MVQ_(p##q3,3);   \
    MVQ_(p##q4,4);   MVQ_(p##q5,5);   MVQ_(p##q6,6);   MVQ_(p##q7,7);   \
    MVQ_(p##q8,8);   MVQ_(p##q9,9);   MVQ_(p##q10,10); MVQ_(p##q11,11); \
    MVQ_(p##q12,12); MVQ_(p##q13,13); MVQ_(p##q14,14); MVQ_(p##q15,15); \
    (outv) = (_a0+_a1)+(_a2+_a3); } while(0)

// One doubling pass over 64 chunk rows (16 waves, 4 rows each):
// dst[i] = src[i] + row.( src[i-dist] ) for i>=dist else copy.
#define DO_PASS4(p, srcb, dstb, dist) do { \
    for (int _r=0;_r<4;++_r){ int _i=w+16*_r; float _val; \
      if (_i>=(dist)) { MV64(p, &(srcb)[_i-(dist)][0], (srcb)[_i][lane], _val); } \
      else _val=(srcb)[_i][lane]; \
      (dstb)[_i][lane]=_val; } } while(0)

// b-projection inner: acc += B-rowchunk (bb0..bb7 in scope) . x[32 floats]
#define BROW(acc, xptr) do { const float4* _x4=(const float4*)(xptr); float4 _xv; \
  _xv=_x4[0]; acc=fmaf(bb0.x,_xv.x,acc); acc=fmaf(bb0.y,_xv.y,acc); acc=fmaf(bb0.z,_xv.z,acc); acc=fmaf(bb0.w,_xv.w,acc); \
  _xv=_x4[1]; acc=fmaf(bb1.x,_xv.x,acc); acc=fmaf(bb1.y,_xv.y,acc); acc=fmaf(bb1.z,_xv.z,acc); acc=fmaf(bb1.w,_xv.w,acc); \
  _xv=_x4[2]; acc=fmaf(bb2.x,_xv.x,acc); acc=fmaf(bb2.y,_xv.y,acc); acc=fmaf(bb2.z,_xv.z,acc); acc=fmaf(bb2.w,_xv.w,acc); \
  _xv=_x4[3]; acc=fmaf(bb3.x,_xv.x,acc); acc=fmaf(bb3.y,_xv.y,acc); acc=fmaf(bb3.z,_xv.z,acc); acc=fmaf(bb3.w,_xv.w,acc); \
  _xv=_x4[4]; acc=fmaf(bb4.x,_xv.x,acc); acc=fmaf(bb4.y,_xv.y,acc); acc=fmaf(bb4.z,_xv.z,acc); acc=fmaf(bb4.w,_xv.w,acc); \
  _xv=_x4[5]; acc=fmaf(bb5.x,_xv.x,acc); acc=fmaf(bb5.y,_xv.y,acc); acc=fmaf(bb5.z,_xv.z,acc); acc=fmaf(bb5.w,_xv.w,acc); \
  _xv=_x4[6]; acc=fmaf(bb6.x,_xv.x,acc); acc=fmaf(bb6.y,_xv.y,acc); acc=fmaf(bb6.z,_xv.z,acc); acc=fmaf(bb6.w,_xv.w,acc); \
  _xv=_x4[7]; acc=fmaf(bb7.x,_xv.x,acc); acc=fmaf(bb7.y,_xv.y,acc); acc=fmaf(bb7.z,_xv.z,acc); acc=fmaf(bb7.w,_xv.w,acc); } while(0)

// ---------------------------------------------------------------------------
// Block-wide (1024 thr) 64x64 matmul in LDS: Md = Ma*Mb; optional global store.
// Scalar accumulators only (no arrays). Ends with __syncthreads.
// ---------------------------------------------------------------------------
__device__ __forceinline__ void mm64(const float* Ma, const float* Mb, float* Md,
                                     float* gout, int tid) {
    const int r = tid >> 4, c0 = (tid & 15) * 4;
    float a0 = 0.f, a1 = 0.f, a2 = 0.f, a3 = 0.f;
    for (int k = 0; k < H_; ++k) {
        const float av = Ma[r * MS + k];
        const float4 bv = *(const float4*)(Mb + k * MS + c0);
        a0 = fmaf(av, bv.x, a0);
        a1 = fmaf(av, bv.y, a1);
        a2 = fmaf(av, bv.z, a2);
        a3 = fmaf(av, bv.w, a3);
    }
    Md[r * MS + c0 + 0] = a0;
    Md[r * MS + c0 + 1] = a1;
    Md[r * MS + c0 + 2] = a2;
    Md[r * MS + c0 + 3] = a3;
    if (gout) {
        gout[r * H_ + c0 + 0] = a0;
        gout[r * H_ + c0 + 1] = a1;
        gout[r * H_ + c0 + 2] = a2;
        gout[r * H_ + c0 + 3] = a3;
    }
    __syncthreads();
}

// ---------------------------------------------------------------------------
// K1: blocks 0..127: bproj of own chunk -> LDS, then interleaved
//     {doubling pass, local squaring} -> chunk-local prefix d -> global.
//     block 128: export P[s] = A^(2^s), s=0..12.
// ---------------------------------------------------------------------------
__global__ __launch_bounds__(1024, 4) void k_chunks(
        const float* __restrict__ x, const float* __restrict__ A_raw,
        const float* __restrict__ B, const float* __restrict__ c,
        float* __restrict__ ws) {
    __shared__ __align__(16) float M1[H_ * MS];
    __shared__ __align__(16) float M2[H_ * MS];
    __shared__ __align__(16) float dbuf[2][L_][H_];
    const int tid = threadIdx.x, lane = tid & 63, w = tid >> 6;
    float* d_pref = ws;
    float* P = ws + OFF_P;

    if (blockIdx.x == C_) {
        // ---- power block: P[s] = A^(2^s) ----
        for (int idx = tid; idx < H_ * H_; idx += 1024) {
            const int r = idx >> 6, k = idx & 63;
            const float val = 0.1f * A_raw[idx] + ((r == k) ? 0.9f : 0.0f);
            M1[r * MS + k] = val;
            P[idx] = val;
        }
        __syncthreads();
        float* src = M1;
        float* dst = M2;
        for (int s = 1; s <= 12; ++s) {
            mm64(src, src, dst, P + s * 4096, tid);
            float* t = src; src = dst; dst = t;
        }
        return;
    }

    const int cid = blockIdx.x;
    // ---- b projection into dbuf[0]: wave w -> rows 4w..4w+3 ----
    {
        const float cc = c[lane];
        float acc0 = cc, acc1 = cc, acc2 = cc, acc3 = cc;
        const float* Brow = B + lane * X_;
        const int t0 = cid * L_ + w * 4;
        for (int kc = 0; kc < 4; ++kc) {
            const float4* _bp = (const float4*)(Brow + kc * 32);
            float4 bb0=_bp[0],bb1=_bp[1],bb2=_bp[2],bb3=_bp[3],
                   bb4=_bp[4],bb5=_bp[5],bb6=_bp[6],bb7=_bp[7];
            BROW(acc0, x + (size_t)(t0 + 0) * X_ + kc * 32);
            BROW(acc1, x + (size_t)(t0 + 1) * X_ + kc * 32);
            BROW(acc2, x + (size_t)(t0 + 2) * X_ + kc * 32);
            BROW(acc3, x + (size_t)(t0 + 3) * X_ + kc * 32);
        }
        dbuf[0][w * 4 + 0][lane] = acc0;
        dbuf[0][w * 4 + 1][lane] = acc1;
        dbuf[0][w * 4 + 2][lane] = acc2;
        dbuf[0][w * 4 + 3][lane] = acc3;
    }
    // ---- load A into M1 for local squarings ----
    for (int idx = tid; idx < H_ * H_; idx += 1024) {
        const int r = idx >> 6, k = idx & 63;
        M1[r * MS + k] = 0.1f * A_raw[idx] + ((r == k) ? 0.9f : 0.0f);
    }
    __syncthreads();

    // ---- interleaved: pass(dist) with row in regs, then square ----
    {
        ROW_DECL(ar);
        ROW_LOAD(ar, A_raw + lane * H_);
        ROW_SCALE01(ar);
        ROW_ADD_DIAG(ar);
        DO_PASS4(ar, dbuf[0], dbuf[1], 1);
        mm64(M1, M1, M2, nullptr, tid);            // M2 = A^2 (ends in barrier)
        ROW_LOAD(ar, M2 + lane * MS);
        DO_PASS4(ar, dbuf[1], dbuf[0], 2);
        mm64(M2, M2, M1, nullptr, tid);            // M1 = A^4
        ROW_LOAD(ar, M1 + lane * MS);
        DO_PASS4(ar, dbuf[0], dbuf[1], 4);
        mm64(M1, M1, M2, nullptr, tid);            // M2 = A^8
        ROW_LOAD(ar, M2 + lane * MS);
        DO_PASS4(ar, dbuf[1], dbuf[0], 8);
        mm64(M2, M2, M1, nullptr, tid);            // M1 = A^16
        ROW_LOAD(ar, M1 + lane * MS);
        DO_PASS4(ar, dbuf[0], dbuf[1], 16);
        mm64(M1, M1, M2, nullptr, tid);            // M2 = A^32
        ROW_LOAD(ar, M2 + lane * MS);
        DO_PASS4(ar, dbuf[1], dbuf[0], 32);
        __syncthreads();
    }
    // ---- write d (chunk-local prefix) ----
    for (int idx = tid; idx < L_ * H_; idx += 1024)
        d_pref[(size_t)cid * L_ * H_ + idx] = dbuf[0][idx >> 6][idx & 63];
}

// ---------------------------------------------------------------------------
// K2: block 0: chunk-level doubling scan over u=[h0, v_0..v_126] with P[6+k].
//     blocks 1..64: G_n = A^n by binary product over P[0..6] -> Gg[n-1].
// ---------------------------------------------------------------------------
__global__ __launch_bounds__(1024, 4) void k_scan_g(
        const float* __restrict__ h0, float* __restrict__ ws) {
    __shared__ __align__(16) float smem[2 * C_ * H_];  // 64 KB
    const int tid = threadIdx.x, lane = tid & 63, w = tid >> 6;
    const float* d_pref = ws;
    const float* P = ws + OFF_P;
    float* hstart = ws + OFF_HS;
    float* Gg = ws + OFF_G;

    if (blockIdx.x == 0) {
        float (*sb0)[H_] = (float (*)[H_])smem;
        float (*sb1)[H_] = (float (*)[H_])(smem + C_ * H_);
        for (int idx = tid; idx < C_ * H_; idx += 1024) {
            const int row = idx >> 6, e = idx & 63;
            sb0[row][e] = (row == 0)
                ? h0[e]
                : d_pref[(size_t)(row - 1) * L_ * H_ + 63 * H_ + e];
        }
        __syncthreads();
        float (*src)[H_] = sb0;
        float (*dst)[H_] = sb1;
        for (int k = 0; k < 7; ++k) {
            const int dist = 1 << k;
            ROW_DECL(ar);
            ROW_LOAD(ar, P + (6 + k) * 4096 + lane * H_);
            for (int r = 0; r < 8; ++r) {
                const int i = w + 16 * r;
                float val;
                if (i >= dist) { MV64(ar, &src[i - dist][0], src[i][lane], val); }
                else val = src[i][lane];
                dst[i][lane] = val;
            }
            __syncthreads();
            float (*t)[H_] = src; src = dst; dst = t;
        }
        for (int idx = tid; idx < C_ * H_; idx += 1024)
            hstart[idx] = src[idx >> 6][idx & 63];
    } else {
        // G block: n = blockIdx.x in 1..64 ; Gg[n-1] = A^n
        float* Mp = smem;
        float* Mf = smem + H_ * MS;
        float* Mo = smem + 2 * H_ * MS;
        const int n = blockIdx.x;
        const int j0 = __ffs(n) - 1;
        for (int idx = tid; idx < H_ * H_; idx += 1024)
            Mp[(idx >> 6) * MS + (idx & 63)] = P[j0 * 4096 + idx];
        __syncthreads();
        for (int j = j0 + 1; j < 7; ++j) {
            if (!((n >> j) & 1)) continue;
            for (int idx = tid; idx < H_ * H_; idx += 1024)
                Mf[(idx >> 6) * MS + (idx & 63)] = P[j * 4096 + idx];
            __syncthreads();
            mm64(Mf, Mp, Mo, nullptr, tid);   // Mo = A^(2^j) * product
            float* t = Mp; Mp = Mo; Mo = t;
        }
        for (int idx = tid; idx < H_ * H_; idx += 1024)
            Gg[(size_t)(n - 1) * 4096 + idx] = Mp[(idx >> 6) * MS + (idx & 63)];
    }
}

// ---------------------------------------------------------------------------
// K3: block i (0..63): out[c*64+i][:] = G_i * s_c + d[c][i][:] for all c.
// ---------------------------------------------------------------------------
__global__ __launch_bounds__(1024, 4) void k_out(
        float* __restrict__ out, const float* __restrict__ ws) {
    __shared__ __align__(16) float S[C_][H_];
    const int tid = threadIdx.x, lane = tid & 63, w = tid >> 6;
    const float* d_pref = ws;
    const float* hstart = ws + OFF_HS;
    const float* Gg = ws + OFF_G;
    const int i = blockIdx.x;

    for (int idx = tid; idx < C_ * H_; idx += 1024)
        S[idx >> 6][idx & 63] = hstart[idx];
    ROW_DECL(gr);
    ROW_LOAD(gr, Gg + (size_t)i * 4096 + lane * H_);
    __syncthreads();

    for (int r = 0; r < 8; ++r) {
        const int cc = w + 16 * r;
        const float dinit = d_pref[(size_t)cc * L_ * H_ + i * H_ + lane];
        float val;
        MV64(gr, &S[cc][0], dinit, val);
        out[((size_t)cc * L_ + i) * H_ + lane] = val;
    }
}

extern "C" void kernel_launch(void* const* d_in, const int* in_sizes, int n_in,
                              void* d_out, int out_size, void* d_ws, size_t ws_size,
                              hipStream_t stream) {
    const float* x     = (const float*)d_in[0];  // [T, X]
    const float* h0    = (const float*)d_in[1];  // [H]
    const float* A_raw = (const float*)d_in[2];  // [H, H]
    const float* B     = (const float*)d_in[3];  // [H, X]
    const float* c     = (const float*)d_in[4];  // [H]
    float* out = (float*)d_out;                  // [T, H]
    float* ws  = (float*)d_ws;

    k_chunks<<<C_ + 1, 1024, 0, stream>>>(x, A_raw, B, c, ws);
    k_scan_g<<<65,     1024, 0, stream>>>(h0, ws);
    k_out   <<<64,     1024, 0, stream>>>(out, ws);
}

// Round 8
// 140.020 us; speedup vs baseline: 1.2390x; 1.2390x over previous
//
#include <hip/hip_runtime.h>
#include <hip/hip_bf16.h>

// Problem constants
#define T_ 8192
#define H_ 64
#define X_ 128
#define C_ 128   // chunks
#define L_ 64    // chunk length
#define MS 68    // matrix LDS row stride (floats): 68%32=4 bank stagger, 16B-aligned
#define VS1 68   // K1 vector buffer stride: 4 zero-pad + 64 t
#define VS2 132  // K2 scan buffer stride: 4 zero-pad + 128 c (132%32=4, 528B rows)

// workspace float offsets
#define OFF_P   (T_ * H_)              // P[13][4096]: A^(2^s), s=0..12
#define OFF_HS  (OFF_P + 13 * 4096)    // hstart[128][64] row-major
#define OFF_G   (OFF_HS + C_ * H_)     // Ggt[64][4096]: (A^(i+1))^T, [k][e]

// ---------------------------------------------------------------------------
// One shifted-matvec output chunk (4 floats over the t/c axis):
//   r[t] = V[e][t] + sum_k M[e][k] * V[k][t-DIST]
// V col-major with 4-float zero pad at the left (data at +4). For DIST<4 the
// shift crosses float4 boundaries: read prev+cur aligned chunks and shuffle.
// For DIST>=4 (multiple of 4): single aligned read; tc<DIST threads copy.
// M stride is MS. All LDS reads are broadcast or contiguous (conflict-free).
// ---------------------------------------------------------------------------
template<int DIST, int STRIDE>
__device__ __forceinline__ float4 shift_mv(const float* V, const float* M,
                                           int e, int tc) {
    float4 own = *(const float4*)(V + e * STRIDE + 4 + tc);
    if (DIST >= 4 && tc < DIST) return own;  // pure copy below the boundary
    float a0 = own.x, a1 = own.y, a2 = own.z, a3 = own.w;
#pragma unroll 8
    for (int k = 0; k < 64; ++k) {
        const float m = M[e * MS + k];
        float4 sh;
        if (DIST < 4) {
            const float4 pr = *(const float4*)(V + k * STRIDE + tc);      // [tc-4..tc-1]+pad
            const float4 cu = *(const float4*)(V + k * STRIDE + 4 + tc);  // [tc..tc+3]
            sh = (DIST == 1) ? make_float4(pr.w, cu.x, cu.y, cu.z)
                             : make_float4(pr.z, pr.w, cu.x, cu.y);
        } else {
            sh = *(const float4*)(V + k * STRIDE + 4 + tc - DIST);
        }
        a0 = fmaf(m, sh.x, a0);
        a1 = fmaf(m, sh.y, a1);
        a2 = fmaf(m, sh.z, a2);
        a3 = fmaf(m, sh.w, a3);
    }
    return make_float4(a0, a1, a2, a3);
}

// ---------------------------------------------------------------------------
// Block-wide (1024 thr) 64x64 matmul in LDS: Md = Ma*Mb; optional row-major
// global store. Scalar accumulators only. Ends with __syncthreads.
// ---------------------------------------------------------------------------
__device__ __forceinline__ void mm64(const float* Ma, const float* Mb, float* Md,
                                     float* gout, int tid) {
    const int r = tid >> 4, c0 = (tid & 15) * 4;
    float a0 = 0.f, a1 = 0.f, a2 = 0.f, a3 = 0.f;
#pragma unroll 8
    for (int k = 0; k < H_; ++k) {
        const float av = Ma[r * MS + k];
        const float4 bv = *(const float4*)(Mb + k * MS + c0);
        a0 = fmaf(av, bv.x, a0);
        a1 = fmaf(av, bv.y, a1);
        a2 = fmaf(av, bv.z, a2);
        a3 = fmaf(av, bv.w, a3);
    }
    Md[r * MS + c0 + 0] = a0;
    Md[r * MS + c0 + 1] = a1;
    Md[r * MS + c0 + 2] = a2;
    Md[r * MS + c0 + 3] = a3;
    if (gout) {
        gout[r * H_ + c0 + 0] = a0;
        gout[r * H_ + c0 + 1] = a1;
        gout[r * H_ + c0 + 2] = a2;
        gout[r * H_ + c0 + 3] = a3;
    }
    __syncthreads();
}

// ---------------------------------------------------------------------------
// K1: blocks 0..127: bproj of own chunk into col-major V[e][t], then 6
//     doubling passes (dist 1..32, matmul-style, in-place reg-staged)
//     interleaved with local squarings -> chunk-local prefix d -> global.
//     block 128: export P[s] = A^(2^s), s=0..12.
// ---------------------------------------------------------------------------
__global__ __launch_bounds__(1024) void k_chunks(
        const float* __restrict__ x, const float* __restrict__ A_raw,
        const float* __restrict__ B, const float* __restrict__ c,
        float* __restrict__ ws) {
    __shared__ __align__(16) float M1[H_ * MS];
    __shared__ __align__(16) float M2[H_ * MS];
    __shared__ __align__(16) float V[H_ * VS1];
    const int tid = threadIdx.x, lane = tid & 63, w = tid >> 6;
    float* d_pref = ws;
    float* P = ws + OFF_P;

    if (blockIdx.x == C_) {
        // ---- power block: P[s] = A^(2^s), s=0..12 ----
        for (int idx = tid; idx < H_ * H_; idx += 1024) {
            const int r = idx >> 6, k = idx & 63;
            const float val = 0.1f * A_raw[idx] + ((r == k) ? 0.9f : 0.0f);
            M1[r * MS + k] = val;
            P[idx] = val;
        }
        __syncthreads();
        float* src = M1;
        float* dst = M2;
        for (int s = 1; s <= 12; ++s) {
            mm64(src, src, dst, P + s * 4096, tid);
            float* t = src; src = dst; dst = t;
        }
        return;
    }

    const int cid = blockIdx.x;
    // ---- b projection into V[e][4+t] (lane = e; wave w -> t rows 4w..4w+3) ----
    {
        const float cc = c[lane];
        float acc0 = cc, acc1 = cc, acc2 = cc, acc3 = cc;
        const float* Brow = B + lane * X_;
        const int t0 = cid * L_ + w * 4;
        for (int kc = 0; kc < 4; ++kc) {
            const float4* bp = (const float4*)(Brow + kc * 32);
            float4 bb0=bp[0],bb1=bp[1],bb2=bp[2],bb3=bp[3],
                   bb4=bp[4],bb5=bp[5],bb6=bp[6],bb7=bp[7];
#define BR1(acc, xptr) do { const float4* x4=(const float4*)(xptr); float4 xv; \
  xv=x4[0]; acc=fmaf(bb0.x,xv.x,acc); acc=fmaf(bb0.y,xv.y,acc); acc=fmaf(bb0.z,xv.z,acc); acc=fmaf(bb0.w,xv.w,acc); \
  xv=x4[1]; acc=fmaf(bb1.x,xv.x,acc); acc=fmaf(bb1.y,xv.y,acc); acc=fmaf(bb1.z,xv.z,acc); acc=fmaf(bb1.w,xv.w,acc); \
  xv=x4[2]; acc=fmaf(bb2.x,xv.x,acc); acc=fmaf(bb2.y,xv.y,acc); acc=fmaf(bb2.z,xv.z,acc); acc=fmaf(bb2.w,xv.w,acc); \
  xv=x4[3]; acc=fmaf(bb3.x,xv.x,acc); acc=fmaf(bb3.y,xv.y,acc); acc=fmaf(bb3.z,xv.z,acc); acc=fmaf(bb3.w,xv.w,acc); \
  xv=x4[4]; acc=fmaf(bb4.x,xv.x,acc); acc=fmaf(bb4.y,xv.y,acc); acc=fmaf(bb4.z,xv.z,acc); acc=fmaf(bb4.w,xv.w,acc); \
  xv=x4[5]; acc=fmaf(bb5.x,xv.x,acc); acc=fmaf(bb5.y,xv.y,acc); acc=fmaf(bb5.z,xv.z,acc); acc=fmaf(bb5.w,xv.w,acc); \
  xv=x4[6]; acc=fmaf(bb6.x,xv.x,acc); acc=fmaf(bb6.y,xv.y,acc); acc=fmaf(bb6.z,xv.z,acc); acc=fmaf(bb6.w,xv.w,acc); \
  xv=x4[7]; acc=fmaf(bb7.x,xv.x,acc); acc=fmaf(bb7.y,xv.y,acc); acc=fmaf(bb7.z,xv.z,acc); acc=fmaf(bb7.w,xv.w,acc); } while(0)
            BR1(acc0, x + (size_t)(t0 + 0) * X_ + kc * 32);
            BR1(acc1, x + (size_t)(t0 + 1) * X_ + kc * 32);
            BR1(acc2, x + (size_t)(t0 + 2) * X_ + kc * 32);
            BR1(acc3, x + (size_t)(t0 + 3) * X_ + kc * 32);
#undef BR1
        }
        const int tb = w * 4;
        V[lane * VS1 + 4 + tb + 0] = acc0;
        V[lane * VS1 + 4 + tb + 1] = acc1;
        V[lane * VS1 + 4 + tb + 2] = acc2;
        V[lane * VS1 + 4 + tb + 3] = acc3;
    }
    // ---- zero pad + load A into M1 ----
    if (tid < 64) {
        V[tid * VS1 + 0] = 0.f; V[tid * VS1 + 1] = 0.f;
        V[tid * VS1 + 2] = 0.f; V[tid * VS1 + 3] = 0.f;
    }
    for (int idx = tid; idx < H_ * H_; idx += 1024) {
        const int r = idx >> 6, k = idx & 63;
        M1[r * MS + k] = 0.1f * A_raw[idx] + ((r == k) ? 0.9f : 0.0f);
    }
    __syncthreads();

    // ---- 6 doubling passes interleaved with squarings ----
    const int pe = tid >> 4, tc = (tid & 15) * 4;
#define K1_PASS(DIST, M) do { \
    float4 r_ = shift_mv<DIST, VS1>(V, M, pe, tc); \
    __syncthreads(); \
    *(float4*)(V + pe * VS1 + 4 + tc) = r_; \
    __syncthreads(); } while(0)
    K1_PASS(1,  M1);
    mm64(M1, M1, M2, nullptr, tid);   // M2 = A^2
    K1_PASS(2,  M2);
    mm64(M2, M2, M1, nullptr, tid);   // M1 = A^4
    K1_PASS(4,  M1);
    mm64(M1, M1, M2, nullptr, tid);   // M2 = A^8
    K1_PASS(8,  M2);
    mm64(M2, M2, M1, nullptr, tid);   // M1 = A^16
    K1_PASS(16, M1);
    mm64(M1, M1, M2, nullptr, tid);   // M2 = A^32
    K1_PASS(32, M2);
#undef K1_PASS

    // ---- transpose-write d: thread (t, e-chunk) -> coalesced global float4 ----
    {
        const int t = tid >> 4, ec = (tid & 15) * 4;
        float4 o;
        o.x = V[(ec + 0) * VS1 + 4 + t];
        o.y = V[(ec + 1) * VS1 + 4 + t];
        o.z = V[(ec + 2) * VS1 + 4 + t];
        o.w = V[(ec + 3) * VS1 + 4 + t];
        *(float4*)(d_pref + ((size_t)(cid * L_ + t) * H_ + ec)) = o;
    }
}

// ---------------------------------------------------------------------------
// K2: block 0: chunk-level doubling scan (7 passes, dist 1..64) over
//     u=[h0, v_0..v_126] in col-major V2[e][c] with Q^(2^k) = P[6+k].
//     blocks 1..64: Ggt[n-1] = (A^n)^T by binary product over P[0..6].
// ---------------------------------------------------------------------------
__global__ __launch_bounds__(1024) void k_scan_g(
        const float* __restrict__ h0, float* __restrict__ ws) {
    __shared__ __align__(16) float smem[13056];  // 52224 B, phase-unioned
    const int tid = threadIdx.x;
    const float* d_pref = ws;
    const float* P = ws + OFF_P;
    float* hstart = ws + OFF_HS;
    float* Ggt = ws + OFF_G;

    if (blockIdx.x == 0) {
        float* V2 = smem;               // [64][VS2]
        float* Mq = smem + H_ * VS2;    // [64][MS]
        // load u col-major: V2[e][4+c]; c=0 -> h0, else v_{c-1}
        for (int idx = tid; idx < C_ * H_; idx += 1024) {
            const int cc2 = idx >> 6, e = idx & 63;
            const float val = (cc2 == 0)
                ? h0[e]
                : d_pref[(size_t)((cc2 - 1) * L_ + 63) * H_ + e];
            V2[e * VS2 + 4 + cc2] = val;
        }
        if (tid < 64) {
            V2[tid * VS2 + 0] = 0.f; V2[tid * VS2 + 1] = 0.f;
            V2[tid * VS2 + 2] = 0.f; V2[tid * VS2 + 3] = 0.f;
        }
        __syncthreads();

        const int e = tid >> 4, cc = (tid & 15) * 4;
#define SCAN_PASS(DIST, KK) do { \
    for (int idx = tid; idx < H_ * H_; idx += 1024) \
        Mq[(idx >> 6) * MS + (idx & 63)] = P[(6 + KK) * 4096 + idx]; \
    __syncthreads(); \
    float4 rA = shift_mv<DIST, VS2>(V2, Mq, e, cc); \
    float4 rB = shift_mv<DIST, VS2>(V2, Mq, e, cc + 64); \
    __syncthreads(); \
    *(float4*)(V2 + e * VS2 + 4 + cc) = rA; \
    *(float4*)(V2 + e * VS2 + 4 + cc + 64) = rB; \
    __syncthreads(); } while(0)
        SCAN_PASS(1, 0);
        SCAN_PASS(2, 1);
        SCAN_PASS(4, 2);
        SCAN_PASS(8, 3);
        SCAN_PASS(16, 4);
        SCAN_PASS(32, 5);
        SCAN_PASS(64, 6);
#undef SCAN_PASS

        // transpose-write hstart[c][e] (coalesced global float4)
        const int c2 = tid >> 4, ec = (tid & 15) * 4;
#pragma unroll
        for (int h2 = 0; h2 < 2; ++h2) {
            const int cc2 = c2 + 64 * h2;
            float4 o;
            o.x = V2[(ec + 0) * VS2 + 4 + cc2];
            o.y = V2[(ec + 1) * VS2 + 4 + cc2];
            o.z = V2[(ec + 2) * VS2 + 4 + cc2];
            o.w = V2[(ec + 3) * VS2 + 4 + cc2];
            *(float4*)(hstart + cc2 * H_ + ec) = o;
        }
    } else {
        // G block: n = blockIdx.x in 1..64 ; Ggt[n-1] = (A^n)^T
        float* Mp = smem;
        float* Mf = smem + H_ * MS;
        float* Mo = smem + 2 * H_ * MS;
        const int n = blockIdx.x;
        const int j0 = __ffs(n) - 1;
        for (int idx = tid; idx < H_ * H_; idx += 1024)
            Mp[(idx >> 6) * MS + (idx & 63)] = P[j0 * 4096 + idx];
        __syncthreads();
        for (int j = j0 + 1; j < 7; ++j) {
            if (!((n >> j) & 1)) continue;
            for (int idx = tid; idx < H_ * H_; idx += 1024)
                Mf[(idx >> 6) * MS + (idx & 63)] = P[j * 4096 + idx];
            __syncthreads();
            mm64(Mf, Mp, Mo, nullptr, tid);   // Mo = A^(2^j) * product
            float* t = Mp; Mp = Mo; Mo = t;
        }
        // transposed store: Ggt[n-1][k][e] = A^n[e][k]
        for (int idx = tid; idx < H_ * H_; idx += 1024)
            Ggt[(size_t)(n - 1) * 4096 + idx] = Mp[(idx & 63) * MS + (idx >> 6)];
    }
}

// ---------------------------------------------------------------------------
// K3: block i (0..63): out[c*64+i][e] = sum_k s_c[k]*Gt[k][e] + d[c][i][e]
//     for all 128 c. Pure LDS GEMM, coalesced global I/O.
// ---------------------------------------------------------------------------
__global__ __launch_bounds__(1024) void k_out(
        float* __restrict__ out, const float* __restrict__ ws) {
    __shared__ __align__(16) float S[C_ * MS];    // [128][MS] s_c row-major
    __shared__ __align__(16) float Gt[H_ * MS];   // [64][MS]  (A^(i+1))^T
    const int tid = threadIdx.x;
    const float* d_pref = ws;
    const float* hstart = ws + OFF_HS;
    const float* Ggt = ws + OFF_G;
    const int i = blockIdx.x;

    for (int idx = tid; idx < C_ * H_; idx += 1024)
        S[(idx >> 6) * MS + (idx & 63)] = hstart[idx];
    for (int idx = tid; idx < H_ * H_; idx += 1024)
        Gt[(idx >> 6) * MS + (idx & 63)] = Ggt[(size_t)i * 4096 + idx];
    __syncthreads();

    const int c2 = tid >> 4, ec = (tid & 15) * 4;
#pragma unroll
    for (int h2 = 0; h2 < 2; ++h2) {
        const int cc = c2 + 64 * h2;
        const size_t base = (size_t)(cc * L_ + i) * H_ + ec;
        float4 acc = *(const float4*)(d_pref + base);
#pragma unroll 8
        for (int k = 0; k < 64; ++k) {
            const float m = S[cc * MS + k];
            const float4 g = *(const float4*)(Gt + k * MS + ec);
            acc.x = fmaf(m, g.x, acc.x);
            acc.y = fmaf(m, g.y, acc.y);
            acc.z = fmaf(m, g.z, acc.z);
            acc.w = fmaf(m, g.w, acc.w);
        }
        *(float4*)(out + base) = acc;
    }
}

extern "C" void kernel_launch(void* const* d_in, const int* in_sizes, int n_in,
                              void* d_out, int out_size, void* d_ws, size_t ws_size,
                              hipStream_t stream) {
    const float* x     = (const float*)d_in[0];  // [T, X]
    const float* h0    = (const float*)d_in[1];  // [H]
    const float* A_raw = (const float*)d_in[2];  // [H, H]
    const float* B     = (const float*)d_in[3];  // [H, X]
    const float* c     = (const float*)d_in[4];  // [H]
    float* out = (float*)d_out;                  // [T, H]
    float* ws  = (float*)d_ws;

    k_chunks<<<C_ + 1, 1024, 0, stream>>>(x, A_raw, B, c, ws);
    k_scan_g<<<65,     1024, 0, stream>>>(h0, ws);
    k_out   <<<64,     1024, 0, stream>>>(out, ws);
}